// Round 2
// baseline (1158.068 us; speedup 1.0000x reference)
//
#include <hip/hip_runtime.h>
#include <hip/hip_bf16.h>
#include <math.h>
#include <stdint.h>

// ---------------------------------------------------------------------------
// GCN: 6 layers of  h' = act( segsum_dst( edge_val * (h @ W)[src] ) + b )
// dims: 512 -> 12 -> 10 -> 8 -> 6 -> 4 -> 7
//
// Round 2: CSR build rebuilt as a bucketed (radix-by-dst>>6) pipeline.
// R1 scatter_kernel wrote 198 MB (7.7x amplification) for a 25.6 MB array
// because per-node cursors scatter 8B stores uniformly over the region.
// Buckets of 64 consecutive dst nodes are contiguous CSR ranges, so:
//   bhist (LDS-hist) -> bscan (bucket_ptr == CSR bucket offsets, free)
//   -> scatter1 (append at 1563 hot L2 cursors, writes cluster at frontiers)
//   -> finalize (block/bucket: LDS in-place reorder to exact CSR, emits row_ptr)
// ---------------------------------------------------------------------------

#define BKT_SH   6                 // 64 nodes per bucket
#define BKT_MAX  2048              // max bucket count supported (N <= 131072)
#define CAP      4096              // max edges per bucket (mean 2048, sigma 45)

// ---- bucket histogram: per-block LDS hist, one flush per block ----
__global__ __launch_bounds__(256) void bhist_kernel(const int* __restrict__ dst,
                                                    int* __restrict__ bhist,
                                                    int E, int nb2) {
    __shared__ int h[BKT_MAX];
    for (int i = threadIdx.x; i < nb2; i += 256) h[i] = 0;
    __syncthreads();
    for (int i = blockIdx.x * 256 + threadIdx.x; i < E; i += gridDim.x * 256)
        atomicAdd(&h[((unsigned)dst[i]) >> BKT_SH], 1);
    __syncthreads();
    for (int i = threadIdx.x; i < nb2; i += 256) {
        int v = h[i];
        if (v) atomicAdd(&bhist[i], v);
    }
}

// ---- exclusive scan of bucket counts (single block) ----
__global__ __launch_bounds__(256) void bscan_kernel(const int* __restrict__ bhist,
                                                    int* __restrict__ bucket_ptr,
                                                    int* __restrict__ bcur, int nb2) {
    __shared__ int part[256];
    int t = threadIdx.x;
    int chunk = (nb2 + 255) / 256;
    int lo = t * chunk;
    int hi = min(lo + chunk, nb2);
    int s = 0;
    for (int i = lo; i < hi; i++) s += bhist[i];
    part[t] = s;
    __syncthreads();
    for (int off = 1; off < 256; off <<= 1) {
        int x = (t >= off) ? part[t - off] : 0;
        __syncthreads();
        part[t] += x;
        __syncthreads();
    }
    int run = part[t] - s;  // exclusive prefix of this chunk
    for (int i = lo; i < hi; i++) {
        bucket_ptr[i] = run;
        bcur[i]       = run;
        run += bhist[i];
    }
    if (t == 255) bucket_ptr[nb2] = run;  // total == E
}

// ---- pass 1: append edges into bucket regions (1563 hot cursors) ----
__global__ __launch_bounds__(256) void scatter1_kernel(const int* __restrict__ src,
                                                       const int* __restrict__ dst,
                                                       const float* __restrict__ val,
                                                       int* __restrict__ bcur,
                                                       int2* __restrict__ edges, int E) {
    int i = blockIdx.x * 256 + threadIdx.x;
    if (i >= E) return;
    int d   = dst[i];
    int pos = atomicAdd(&bcur[d >> BKT_SH], 1);
    // pack: src (17 bits) | local-dst (6 bits, bits 17..22); val bits in .y
    edges[pos] = make_int2(src[i] | ((d & 63) << 17), __float_as_int(val[i]));
}

// ---- pass 2: per-bucket in-place reorder to exact CSR + emit row_ptr ----
__global__ __launch_bounds__(256) void finalize_kernel(int2* __restrict__ edges,
                                                       const int* __restrict__ bucket_ptr,
                                                       int* __restrict__ row_ptr,
                                                       int N) {
    __shared__ int2 recs[CAP];
    __shared__ int cnt[64];
    __shared__ int offs[64];
    __shared__ int cur[64];
    const int b  = blockIdx.x;
    const int t  = threadIdx.x;
    const int s0 = bucket_ptr[b];
    const int s1 = bucket_ptr[b + 1];
    int ne = s1 - s0;
    if (ne > CAP) ne = CAP;  // statistically unreachable (17+ sigma); avoids LDS OOB
    if (t < 64) cnt[t] = 0;
    __syncthreads();
    for (int i = t; i < ne; i += 256) {
        int2 r = edges[s0 + i];
        recs[i] = r;
        atomicAdd(&cnt[(r.x >> 17) & 63], 1);
    }
    __syncthreads();
    if (t == 0) {
        int run = 0;
        for (int i = 0; i < 64; i++) { offs[i] = run; run += cnt[i]; }
    }
    __syncthreads();
    if (t < 64) {
        cur[t] = offs[t];
        int idx = (b << BKT_SH) + t;
        if (idx <= N) row_ptr[idx] = s0 + offs[t];  // covers row_ptr[N] in last bucket
    }
    __syncthreads();
    for (int i = t; i < ne; i += 256) {
        int2 r  = recs[i];
        int  ld = (r.x >> 17) & 63;
        int  p  = atomicAdd(&cur[ld], 1);
        edges[s0 + p] = make_int2(r.x & 0x1FFFF, r.y);
    }
}

// ---------------- layer 1 dense: s = x @ W1  (N x 512) @ (512 x 12) ----------------
__global__ __launch_bounds__(256) void dense1_kernel(const float* __restrict__ x,
                                                     const float* __restrict__ W,
                                                     float* __restrict__ out, int N) {
    __shared__ float xs[256 * 33];
    const int t    = threadIdx.x;
    const int row0 = blockIdx.x * 256;
    const int r    = row0 + t;

    float acc[12];
#pragma unroll
    for (int j = 0; j < 12; j++) acc[j] = 0.f;

    for (int tile = 0; tile < 16; ++tile) {
#pragma unroll
        for (int i = 0; i < 8; i++) {
            int idx4 = t + 256 * i;
            int flat = idx4 * 4;
            int rl   = flat >> 5;
            int c    = flat & 31;
            int rg   = row0 + rl;
            if (rg >= N) rg = N - 1;
            const float4 v = *(const float4*)(x + (size_t)rg * 512 + tile * 32 + c);
            float* p = &xs[rl * 33 + c];
            p[0] = v.x; p[1] = v.y; p[2] = v.z; p[3] = v.w;
        }
        __syncthreads();
#pragma unroll 8
        for (int kk = 0; kk < 32; ++kk) {
            float xv = xs[t * 33 + kk];
            int k = tile * 32 + kk;
#pragma unroll
            for (int j = 0; j < 12; j++) acc[j] += xv * W[k * 12 + j];
        }
        __syncthreads();
    }
    if (r < N) {
#pragma unroll
        for (int j = 0; j < 12; j++) out[(size_t)r * 12 + j] = acc[j];
    }
}

// ---------------- small dense layers: s = act(in + b_prev) @ W ----------------
// ACT: 0 = none, 1 = relu, 2 = tanhshrink
template <int DIN, int DOUT, int ACT>
__global__ void dense_small_kernel(const float* __restrict__ in, const float* __restrict__ bias,
                                   const float* __restrict__ W, float* __restrict__ out, int N) {
    int r = blockIdx.x * blockDim.x + threadIdx.x;
    if (r >= N) return;
    float v[DIN];
#pragma unroll
    for (int k = 0; k < DIN; k++) {
        float h = in[(size_t)r * DIN + k] + bias[k];
        if (ACT == 1) h = fmaxf(h, 0.f);
        else if (ACT == 2) h = h - tanhf(h);
        v[k] = h;
    }
#pragma unroll
    for (int j = 0; j < DOUT; j++) {
        float s = 0.f;
#pragma unroll
        for (int k = 0; k < DIN; k++) s += v[k] * W[k * DOUT + j];
        out[(size_t)r * DOUT + j] = s;
    }
}

// ---------------- CSR gather: agg[n,j] = sum_e val_e * s[src_e, j] ----------------
template <int D, bool FINAL>
__global__ void gather_kernel(const int2* __restrict__ edges, const int* __restrict__ row_ptr,
                              const float* __restrict__ s, const float* __restrict__ bias,
                              float* __restrict__ out, int N) {
    int tid  = blockIdx.x * blockDim.x + threadIdx.x;
    int node = tid / D;
    int j    = tid % D;
    if (node >= N) return;
    int e0 = row_ptr[node];
    int e1 = row_ptr[node + 1];
    float acc = 0.f;
    int e = e0;
    for (; e + 1 < e1; e += 2) {          // 2-way ILP
        int2 ev0 = edges[e];
        int2 ev1 = edges[e + 1];
        acc += __int_as_float(ev0.y) * s[(size_t)ev0.x * D + j];
        acc += __int_as_float(ev1.y) * s[(size_t)ev1.x * D + j];
    }
    if (e < e1) {
        int2 ev = edges[e];
        acc += __int_as_float(ev.y) * s[(size_t)ev.x * D + j];
    }
    if (FINAL) acc += bias[j];
    out[(size_t)node * D + j] = acc;
}

// ---------------- launcher ----------------

static inline size_t align256(size_t x) { return (x + 255) & ~(size_t)255; }

extern "C" void kernel_launch(void* const* d_in, const int* in_sizes, int n_in,
                              void* d_out, int out_size, void* d_ws, size_t ws_size,
                              hipStream_t stream) {
    const float* x        = (const float*)d_in[0];
    const float* edge_val = (const float*)d_in[1];
    const int*   edge_src = (const int*)d_in[2];
    const int*   edge_dst = (const int*)d_in[3];
    const float* W1 = (const float*)d_in[4];   const float* b1 = (const float*)d_in[5];
    const float* W2 = (const float*)d_in[6];   const float* b2 = (const float*)d_in[7];
    const float* W3 = (const float*)d_in[8];   const float* b3 = (const float*)d_in[9];
    const float* W4 = (const float*)d_in[10];  const float* b4 = (const float*)d_in[11];
    const float* W5 = (const float*)d_in[12];  const float* b5 = (const float*)d_in[13];
    const float* W6 = (const float*)d_in[14];  const float* b6 = (const float*)d_in[15];

    const int N = in_sizes[0] / 512;   // 100000
    const int E = in_sizes[1];         // 3200000
    float* out = (float*)d_out;

    const int nb2 = (N + 63) >> BKT_SH;  // buckets (1563)
    const int nb  = (N + 255) / 256;
    const int ebl = (E + 255) / 256;

    // workspace carve-up (256B aligned regions)
    char* w = (char*)d_ws;
    float* A          = (float*)w;  w += align256((size_t)N * 12 * sizeof(float));
    float* B          = (float*)w;  w += align256((size_t)N * 12 * sizeof(float));
    int*   bhist      = (int*)w;    w += align256((size_t)BKT_MAX * sizeof(int));
    int*   bucket_ptr = (int*)w;    w += align256((size_t)(nb2 + 1) * sizeof(int));
    int*   bcur       = (int*)w;    w += align256((size_t)nb2 * sizeof(int));
    int*   row_ptr    = (int*)w;    w += align256((size_t)(N + 1) * sizeof(int));
    int2*  edges      = (int2*)w;   w += align256((size_t)E * sizeof(int2));

    // ---- CSR build (bucketed two-pass; once per launch, reused by 6 layers) ----
    hipMemsetAsync(bhist, 0, (size_t)BKT_MAX * sizeof(int), stream);
    bhist_kernel<<<512, 256, 0, stream>>>(edge_dst, bhist, E, nb2);
    bscan_kernel<<<1, 256, 0, stream>>>(bhist, bucket_ptr, bcur, nb2);
    scatter1_kernel<<<ebl, 256, 0, stream>>>(edge_src, edge_dst, edge_val, bcur, edges, E);
    finalize_kernel<<<nb2, 256, 0, stream>>>(edges, bucket_ptr, row_ptr, N);

    // ---- layer 1: s1 = x @ W1 ; agg -> B ----
    dense1_kernel<<<nb, 256, 0, stream>>>(x, W1, A, N);
    gather_kernel<12, false><<<(int)(((size_t)N * 12 + 255) / 256), 256, 0, stream>>>(edges, row_ptr, A, b1, B, N);

    // ---- layer 2: s2 = (B + b1) @ W2 ; agg -> B ----
    dense_small_kernel<12, 10, 0><<<nb, 256, 0, stream>>>(B, b1, W2, A, N);
    gather_kernel<10, false><<<(int)(((size_t)N * 10 + 255) / 256), 256, 0, stream>>>(edges, row_ptr, A, b2, B, N);

    // ---- layer 3: s3 = relu(B + b2) @ W3 ----
    dense_small_kernel<10, 8, 1><<<nb, 256, 0, stream>>>(B, b2, W3, A, N);
    gather_kernel<8, false><<<(int)(((size_t)N * 8 + 255) / 256), 256, 0, stream>>>(edges, row_ptr, A, b3, B, N);

    // ---- layer 4: s4 = tanhshrink(B + b3) @ W4 ----
    dense_small_kernel<8, 6, 2><<<nb, 256, 0, stream>>>(B, b3, W4, A, N);
    gather_kernel<6, false><<<(int)(((size_t)N * 6 + 255) / 256), 256, 0, stream>>>(edges, row_ptr, A, b4, B, N);

    // ---- layer 5: s5 = tanhshrink(B + b4) @ W5 ----
    dense_small_kernel<6, 4, 2><<<nb, 256, 0, stream>>>(B, b4, W5, A, N);
    gather_kernel<4, false><<<(int)(((size_t)N * 4 + 255) / 256), 256, 0, stream>>>(edges, row_ptr, A, b5, B, N);

    // ---- layer 6: s6 = (B + b5) @ W6 ; agg + b6 -> out ----
    dense_small_kernel<4, 7, 0><<<nb, 256, 0, stream>>>(B, b5, W6, A, N);
    gather_kernel<7, true><<<(int)(((size_t)N * 7 + 255) / 256), 256, 0, stream>>>(edges, row_ptr, A, b6, out, N);
}

// Round 3
// 834.321 us; speedup vs baseline: 1.3880x; 1.3880x over previous
//
#include <hip/hip_runtime.h>
#include <hip/hip_bf16.h>
#include <math.h>
#include <stdint.h>

// ---------------------------------------------------------------------------
// GCN: 6 layers of  h' = act( segsum_dst( edge_val * (h @ W)[src] ) + b )
// dims: 512 -> 12 -> 10 -> 8 -> 6 -> 4 -> 7
//
// Round 3:
//  * CSR build = atomic-free radix partition by dst>>6 (1563 buckets):
//      hist (per-tile LDS hist) -> scanA/B/C (exact per-(tile,bucket) offsets)
//      -> scatter (LDS counting-sort of 12800-edge tiles, run-writes ~65 B,
//         each line written by one block => no cross-XCD write amplification)
//      -> finalize (per-bucket LDS reorder to exact CSR, coalesced writeback).
//    R2 lesson: frontier lines written from 8 XCDs' non-coherent L2s evict
//    partial => 7x write amp; contended device atomics ping-pong lines.
//  * Gather: thread-per-node, float4 s-row loads, fused with next dense layer
//    (bias+act+matmul, W via wave-uniform scalar loads). 13 dispatches total.
// ---------------------------------------------------------------------------

#define T_EDGES 12800   // edges per tile (E=3.2M -> exactly 250 tiles)
#define NB_MAX  1600    // max fine buckets (N<=102400)
#define FCAP    2560    // max edges per 64-node bucket (mean 2048, sigma 45)

// ---- per-tile bucket histogram ----
__global__ __launch_bounds__(256) void hist_kernel(const int* __restrict__ dst,
                                                   int* __restrict__ ghist, int E, int NB) {
    __shared__ int h[NB_MAX];
    for (int i = threadIdx.x; i < NB; i += 256) h[i] = 0;
    __syncthreads();
    int base = blockIdx.x * T_EDGES;
    int n = min(T_EDGES, E - base);
    for (int i = threadIdx.x; i < n; i += 256)
        atomicAdd(&h[((unsigned)dst[base + i]) >> 6], 1);
    __syncthreads();
    for (int i = threadIdx.x; i < NB; i += 256)
        ghist[(size_t)blockIdx.x * NB + i] = h[i];
}

// ---- per-bucket totals (block per bucket; NT <= 256) ----
__global__ __launch_bounds__(256) void scanA_kernel(const int* __restrict__ ghist,
                                                    int* __restrict__ btot, int NT, int NB) {
    __shared__ int red[256];
    int b = blockIdx.x, t = threadIdx.x;
    int s = 0;
    for (int tt = t; tt < NT; tt += 256) s += ghist[(size_t)tt * NB + b];
    red[t] = s;
    __syncthreads();
    for (int off = 128; off > 0; off >>= 1) {
        if (t < off) red[t] += red[t + off];
        __syncthreads();
    }
    if (t == 0) btot[b] = red[0];
}

// ---- exclusive scan over bucket totals -> bucket bases (single block) ----
__global__ __launch_bounds__(256) void scanB_kernel(const int* __restrict__ btot,
                                                    int* __restrict__ bbase,
                                                    int* __restrict__ bucket_ptr, int NB) {
    __shared__ int part[256];
    int t = threadIdx.x;
    int chunk = (NB + 255) / 256;
    int lo = t * chunk, hi = min(lo + chunk, NB);
    int s = 0;
    for (int i = lo; i < hi; i++) s += btot[i];
    part[t] = s;
    __syncthreads();
    for (int off = 1; off < 256; off <<= 1) {
        int x = (t >= off) ? part[t - off] : 0;
        __syncthreads();
        part[t] += x;
        __syncthreads();
    }
    int run = part[t] - s;
    for (int i = lo; i < hi; i++) {
        bbase[i] = run;
        bucket_ptr[i] = run;
        run += btot[i];
    }
    if (t == 255) bucket_ptr[NB] = run;  // == E
}

// ---- per-(tile,bucket) exact global offsets (block per bucket; NT <= 256) ----
__global__ __launch_bounds__(256) void scanC_kernel(const int* __restrict__ ghist,
                                                    const int* __restrict__ bbase,
                                                    int* __restrict__ goff, int NT, int NB) {
    __shared__ int part[256];
    int b = blockIdx.x, t = threadIdx.x;
    int v = (t < NT) ? ghist[(size_t)t * NB + b] : 0;
    part[t] = v;
    __syncthreads();
    for (int off = 1; off < 256; off <<= 1) {
        int x = (t >= off) ? part[t - off] : 0;
        __syncthreads();
        part[t] += x;
        __syncthreads();
    }
    if (t < NT) goff[(size_t)t * NB + b] = bbase[b] + part[t] - v;
}

// ---- scatter: LDS counting-sort per tile, run-writes to exact offsets ----
__global__ __launch_bounds__(256) void scatter_kernel(const int* __restrict__ src,
                                                      const int* __restrict__ dst,
                                                      const float* __restrict__ val,
                                                      const int* __restrict__ ghist,
                                                      const int* __restrict__ goff,
                                                      int2* __restrict__ edges, int E, int NB) {
    __shared__ unsigned perm[T_EDGES];   // 51200 B
    __shared__ int loff[NB_MAX];         // 6400 B
    __shared__ int lcur[NB_MAX];         // 6400 B
    __shared__ int part[256];            // 1024 B  (total 65024 <= 64 KB)
    int tb = blockIdx.x, t = threadIdx.x;
    int base = tb * T_EDGES;
    int n = min(T_EDGES, E - base);

    // local exclusive scan of this tile's hist row -> loff, lcur
    int chunk = (NB + 255) / 256;
    int lo = t * chunk, hi = min(lo + chunk, NB);
    int s = 0;
    for (int i = lo; i < hi; i++) {
        int c = ghist[(size_t)tb * NB + i];
        loff[i] = c;  // temp: counts
        s += c;
    }
    part[t] = s;
    __syncthreads();
    for (int off = 1; off < 256; off <<= 1) {
        int x = (t >= off) ? part[t - off] : 0;
        __syncthreads();
        part[t] += x;
        __syncthreads();
    }
    int run = part[t] - s;
    for (int i = lo; i < hi; i++) {
        int c = loff[i];
        loff[i] = run;
        lcur[i] = run;
        run += c;
    }
    __syncthreads();

    // rank phase: perm[pos within tile] = local_idx | (bucket << 14)
    for (int i = t; i < n; i += 256) {
        unsigned b = ((unsigned)dst[base + i]) >> 6;
        int p = atomicAdd(&lcur[b], 1);       // LDS atomic, avg 8/bin
        perm[p] = (unsigned)i | (b << 14);
    }
    __syncthreads();

    // output phase: coalesced-run stores to exact global positions
    for (int o = t; o < n; o += 256) {
        unsigned v = perm[o];
        int li = v & 16383;
        int b  = v >> 14;
        int g  = goff[(size_t)tb * NB + b] + (o - loff[b]);
        int d  = dst[base + li];
        edges[g] = make_int2(src[base + li] | ((d & 63) << 17), __float_as_int(val[base + li]));
    }
}

// ---- finalize: per-bucket LDS reorder to exact CSR + row_ptr ----
__global__ __launch_bounds__(256) void finalize_kernel(int2* __restrict__ edges,
                                                       const int* __restrict__ bucket_ptr,
                                                       int* __restrict__ row_ptr, int N) {
    __shared__ int2 recs[FCAP];
    __shared__ int2 recs2[FCAP];
    __shared__ int cnt[64], offs[64], cur[64];
    int b = blockIdx.x, t = threadIdx.x;
    int s0 = bucket_ptr[b], s1 = bucket_ptr[b + 1];
    int ne = min(s1 - s0, FCAP);
    if (t < 64) cnt[t] = 0;
    __syncthreads();
    for (int i = t; i < ne; i += 256) {
        int2 r = edges[s0 + i];
        recs[i] = r;
        atomicAdd(&cnt[(r.x >> 17) & 63], 1);
    }
    __syncthreads();
    if (t == 0) {
        int run = 0;
        for (int i = 0; i < 64; i++) { offs[i] = run; run += cnt[i]; }
    }
    __syncthreads();
    if (t < 64) {
        cur[t] = offs[t];
        int idx = (b << 6) + t;
        if (idx <= N) row_ptr[idx] = s0 + offs[t];  // row_ptr[N] covered (N%64=32)
    }
    __syncthreads();
    for (int i = t; i < ne; i += 256) {
        int2 r = recs[i];
        int ld = (r.x >> 17) & 63;
        int p = atomicAdd(&cur[ld], 1);
        recs2[p] = make_int2(r.x & 0x1FFFF, r.y);
    }
    __syncthreads();
    for (int i = t; i < ne; i += 256) edges[s0 + i] = recs2[i];  // coalesced
}

// ---- layer 1 dense: s1 = x @ W1  (N x 512) @ (512 x 12), out stride 12 ----
__global__ __launch_bounds__(256) void dense1_kernel(const float* __restrict__ x,
                                                     const float* __restrict__ W,
                                                     float* __restrict__ out, int N) {
    __shared__ float xs[256 * 33];
    const int t    = threadIdx.x;
    const int row0 = blockIdx.x * 256;
    const int r    = row0 + t;

    float acc[12];
#pragma unroll
    for (int j = 0; j < 12; j++) acc[j] = 0.f;

    for (int tile = 0; tile < 16; ++tile) {
#pragma unroll
        for (int i = 0; i < 8; i++) {
            int idx4 = t + 256 * i;
            int flat = idx4 * 4;
            int rl   = flat >> 5;
            int c    = flat & 31;
            int rg   = row0 + rl;
            if (rg >= N) rg = N - 1;
            const float4 v = *(const float4*)(x + (size_t)rg * 512 + tile * 32 + c);
            float* p = &xs[rl * 33 + c];
            p[0] = v.x; p[1] = v.y; p[2] = v.z; p[3] = v.w;
        }
        __syncthreads();
#pragma unroll 8
        for (int kk = 0; kk < 32; ++kk) {
            float xv = xs[t * 33 + kk];
            int k = tile * 32 + kk;
#pragma unroll
            for (int j = 0; j < 12; j++) acc[j] += xv * W[k * 12 + j];
        }
        __syncthreads();
    }
    if (r < N) {
#pragma unroll
        for (int j = 0; j < 12; j++) out[(size_t)r * 12 + j] = acc[j];
    }
}

// ---- fused layer: agg_k (CSR gather) + h=act(agg+b_k) + s_{k+1}=h@W_{k+1} ----
// NV   = float4s per s-row (input stride = 4*NV floats, pads zeroed upstream)
// ACT: 0 none, 1 relu, 2 tanhshrink.  FINAL: write h (=agg+b) as DIN floats.
template <int NV, int DIN, int DOUT, int OSTR, int ACT, bool FINAL>
__global__ __launch_bounds__(256) void layer_kernel(const int2* __restrict__ edges,
                                                    const int* __restrict__ row_ptr,
                                                    const float* __restrict__ s,
                                                    const float* __restrict__ bias,
                                                    const float* __restrict__ W,
                                                    float* __restrict__ out, int N) {
    int nidx = blockIdx.x * 256 + threadIdx.x;
    if (nidx >= N) return;
    int e0 = row_ptr[nidx], e1 = row_ptr[nidx + 1];
    float4 acc[NV];
#pragma unroll
    for (int v = 0; v < NV; v++) acc[v] = make_float4(0.f, 0.f, 0.f, 0.f);
    const float4* sv = (const float4*)s;
    for (int e = e0; e < e1; ++e) {
        int2 ev = edges[e];
        float w = __int_as_float(ev.y);
        const float4* srow = sv + (size_t)ev.x * NV;
#pragma unroll
        for (int v = 0; v < NV; v++) {
            float4 xr = srow[v];
            acc[v].x += w * xr.x; acc[v].y += w * xr.y;
            acc[v].z += w * xr.z; acc[v].w += w * xr.w;
        }
    }
    float h[NV * 4];
#pragma unroll
    for (int v = 0; v < NV; v++) {
        h[4 * v + 0] = acc[v].x; h[4 * v + 1] = acc[v].y;
        h[4 * v + 2] = acc[v].z; h[4 * v + 3] = acc[v].w;
    }
#pragma unroll
    for (int k = 0; k < DIN; k++) {
        float z = h[k] + bias[k];                 // bias: wave-uniform s_load
        if (ACT == 1) z = fmaxf(z, 0.f);
        else if (ACT == 2) z = z - tanhf(z);
        h[k] = z;
    }
    if (FINAL) {
#pragma unroll
        for (int k = 0; k < DIN; k++) out[(size_t)nidx * DIN + k] = h[k];
    } else {
        float o[OSTR];
#pragma unroll
        for (int j = 0; j < OSTR; j++) o[j] = 0.f;  // zero pads
#pragma unroll
        for (int j = 0; j < DOUT; j++) {
            float tj = 0.f;
#pragma unroll
            for (int k = 0; k < DIN; k++) tj += h[k] * W[k * DOUT + j];  // s_load W
            o[j] = tj;
        }
        float4* orow = (float4*)(out + (size_t)nidx * OSTR);
#pragma unroll
        for (int v = 0; v < OSTR / 4; v++)
            orow[v] = make_float4(o[4 * v], o[4 * v + 1], o[4 * v + 2], o[4 * v + 3]);
    }
}

// ---------------- launcher ----------------

static inline size_t align256(size_t x) { return (x + 255) & ~(size_t)255; }

extern "C" void kernel_launch(void* const* d_in, const int* in_sizes, int n_in,
                              void* d_out, int out_size, void* d_ws, size_t ws_size,
                              hipStream_t stream) {
    const float* x        = (const float*)d_in[0];
    const float* edge_val = (const float*)d_in[1];
    const int*   edge_src = (const int*)d_in[2];
    const int*   edge_dst = (const int*)d_in[3];
    const float* W1 = (const float*)d_in[4];   const float* b1 = (const float*)d_in[5];
    const float* W2 = (const float*)d_in[6];   const float* b2 = (const float*)d_in[7];
    const float* W3 = (const float*)d_in[8];   const float* b3 = (const float*)d_in[9];
    const float* W4 = (const float*)d_in[10];  const float* b4 = (const float*)d_in[11];
    const float* W5 = (const float*)d_in[12];  const float* b5 = (const float*)d_in[13];
    const float* W6 = (const float*)d_in[14];  const float* b6 = (const float*)d_in[15];

    const int N = in_sizes[0] / 512;        // 100000
    const int E = in_sizes[1];              // 3200000
    float* out = (float*)d_out;

    const int NB = (N + 63) >> 6;           // 1563 fine buckets
    const int NT = (E + T_EDGES - 1) / T_EDGES;  // 250 tiles (<=256 required)
    const int nb = (N + 255) / 256;

    // workspace carve-up (~38.7 MB)
    char* w = (char*)d_ws;
    float* A          = (float*)w;  w += align256((size_t)N * 12 * sizeof(float));
    float* B          = (float*)w;  w += align256((size_t)N * 12 * sizeof(float));
    int*   ghist      = (int*)w;    w += align256((size_t)NT * NB * sizeof(int));
    int*   goff       = (int*)w;    w += align256((size_t)NT * NB * sizeof(int));
    int*   btot       = (int*)w;    w += align256((size_t)NB * sizeof(int));
    int*   bbase      = (int*)w;    w += align256((size_t)NB * sizeof(int));
    int*   bucket_ptr = (int*)w;    w += align256((size_t)(NB + 1) * sizeof(int));
    int*   row_ptr    = (int*)w;    w += align256((size_t)(N + 1) * sizeof(int));
    int2*  edges      = (int2*)w;   w += align256((size_t)E * sizeof(int2));

    // ---- CSR build: atomic-free radix partition ----
    hist_kernel<<<NT, 256, 0, stream>>>(edge_dst, ghist, E, NB);
    scanA_kernel<<<NB, 256, 0, stream>>>(ghist, btot, NT, NB);
    scanB_kernel<<<1, 256, 0, stream>>>(btot, bbase, bucket_ptr, NB);
    scanC_kernel<<<NB, 256, 0, stream>>>(ghist, bbase, goff, NT, NB);
    scatter_kernel<<<NT, 256, 0, stream>>>(edge_src, edge_dst, edge_val, ghist, goff, edges, E, NB);
    finalize_kernel<<<NB, 256, 0, stream>>>(edges, bucket_ptr, row_ptr, N);

    // ---- dense1: s1 = x @ W1 (stride 12) ----
    dense1_kernel<<<nb, 256, 0, stream>>>(x, W1, A, N);

    // ---- fused gather+dense chain ----
    // G1: agg1 -> h1=agg+b1 -> s2=h1@W2 (12->10, out stride 12)
    layer_kernel<3, 12, 10, 12, 0, false><<<nb, 256, 0, stream>>>(edges, row_ptr, A, b1, W2, B, N);
    // G2: agg2 -> h2=relu(agg+b2) -> s3=h2@W3 (10->8, out stride 8)
    layer_kernel<3, 10, 8, 8, 1, false><<<nb, 256, 0, stream>>>(edges, row_ptr, B, b2, W3, A, N);
    // G3: agg3 -> h3=ts(agg+b3) -> s4=h3@W4 (8->6, out stride 8)
    layer_kernel<2, 8, 6, 8, 2, false><<<nb, 256, 0, stream>>>(edges, row_ptr, A, b3, W4, B, N);
    // G4: agg4 -> h4=ts(agg+b4) -> s5=h4@W5 (6->4, out stride 4)
    layer_kernel<2, 6, 4, 4, 2, false><<<nb, 256, 0, stream>>>(edges, row_ptr, B, b4, W5, A, N);
    // G5: agg5 -> h5=agg+b5 -> s6=h5@W6 (4->7, out stride 8)
    layer_kernel<1, 4, 7, 8, 0, false><<<nb, 256, 0, stream>>>(edges, row_ptr, A, b5, W6, B, N);
    // G6: out = agg6 + b6 (7, exact layout)
    layer_kernel<2, 7, 7, 8, 0, true><<<nb, 256, 0, stream>>>(edges, row_ptr, B, b6, (const float*)nullptr, out, N);
}

// Round 4
// 746.268 us; speedup vs baseline: 1.5518x; 1.1180x over previous
//
#include <hip/hip_runtime.h>
#include <hip/hip_bf16.h>
#include <math.h>
#include <stdint.h>

// ---------------------------------------------------------------------------
// GCN: 6 layers of  h' = act( segsum_dst( edge_val * (h @ W)[src] ) + b )
// dims: 512 -> 12 -> 10 -> 8 -> 6 -> 4 -> 7
//
// Round 4: gather layers rebuilt bucket-parallel. R3's thread-per-node gather
// was latency-bound: 100K threads = 6 waves/CU, each a ~32-step dependent
// edge->s-row load chain (~100us/layer). Now: block-per-bucket (1563 blocks,
// 24 waves/CU), edges staged coalesced into LDS, per-thread run-accumulation
// over ~8 sorted edges (NV independent float4 gathers per edge), LDS-atomic
// flush into 64x13 accumulator, fused bias/act/next-matmul epilogue.
// CSR build: atomic-free radix partition by dst>>6 (R3, kept; row_ptr dropped).
// ---------------------------------------------------------------------------

#define T_EDGES 12800   // edges per tile (E=3.2M -> exactly 250 tiles)
#define NB_MAX  1600    // max fine buckets (N<=102400)
#define FCAP    2560    // max edges per 64-node bucket (mean 2048, sigma 45)

// ---- per-tile bucket histogram ----
__global__ __launch_bounds__(256) void hist_kernel(const int* __restrict__ dst,
                                                   int* __restrict__ ghist, int E, int NB) {
    __shared__ int h[NB_MAX];
    for (int i = threadIdx.x; i < NB; i += 256) h[i] = 0;
    __syncthreads();
    int base = blockIdx.x * T_EDGES;
    int n = min(T_EDGES, E - base);
    for (int i = threadIdx.x; i < n; i += 256)
        atomicAdd(&h[((unsigned)dst[base + i]) >> 6], 1);
    __syncthreads();
    for (int i = threadIdx.x; i < NB; i += 256)
        ghist[(size_t)blockIdx.x * NB + i] = h[i];
}

// ---- per-bucket totals (block per bucket; NT <= 256) ----
__global__ __launch_bounds__(256) void scanA_kernel(const int* __restrict__ ghist,
                                                    int* __restrict__ btot, int NT, int NB) {
    __shared__ int red[256];
    int b = blockIdx.x, t = threadIdx.x;
    int s = 0;
    for (int tt = t; tt < NT; tt += 256) s += ghist[(size_t)tt * NB + b];
    red[t] = s;
    __syncthreads();
    for (int off = 128; off > 0; off >>= 1) {
        if (t < off) red[t] += red[t + off];
        __syncthreads();
    }
    if (t == 0) btot[b] = red[0];
}

// ---- exclusive scan over bucket totals -> bucket bases (single block) ----
__global__ __launch_bounds__(256) void scanB_kernel(const int* __restrict__ btot,
                                                    int* __restrict__ bbase,
                                                    int* __restrict__ bucket_ptr, int NB) {
    __shared__ int part[256];
    int t = threadIdx.x;
    int chunk = (NB + 255) / 256;
    int lo = t * chunk, hi = min(lo + chunk, NB);
    int s = 0;
    for (int i = lo; i < hi; i++) s += btot[i];
    part[t] = s;
    __syncthreads();
    for (int off = 1; off < 256; off <<= 1) {
        int x = (t >= off) ? part[t - off] : 0;
        __syncthreads();
        part[t] += x;
        __syncthreads();
    }
    int run = part[t] - s;
    for (int i = lo; i < hi; i++) {
        bbase[i] = run;
        bucket_ptr[i] = run;
        run += btot[i];
    }
    if (t == 255) bucket_ptr[NB] = run;  // == E
}

// ---- per-(tile,bucket) exact global offsets (block per bucket; NT <= 256) ----
__global__ __launch_bounds__(256) void scanC_kernel(const int* __restrict__ ghist,
                                                    const int* __restrict__ bbase,
                                                    int* __restrict__ goff, int NT, int NB) {
    __shared__ int part[256];
    int b = blockIdx.x, t = threadIdx.x;
    int v = (t < NT) ? ghist[(size_t)t * NB + b] : 0;
    part[t] = v;
    __syncthreads();
    for (int off = 1; off < 256; off <<= 1) {
        int x = (t >= off) ? part[t - off] : 0;
        __syncthreads();
        part[t] += x;
        __syncthreads();
    }
    if (t < NT) goff[(size_t)t * NB + b] = bbase[b] + part[t] - v;
}

// ---- scatter: LDS counting-sort per tile, run-writes to exact offsets ----
__global__ __launch_bounds__(256) void scatter_kernel(const int* __restrict__ src,
                                                      const int* __restrict__ dst,
                                                      const float* __restrict__ val,
                                                      const int* __restrict__ ghist,
                                                      const int* __restrict__ goff,
                                                      int2* __restrict__ edges, int E, int NB) {
    __shared__ unsigned perm[T_EDGES];   // 51200 B
    __shared__ int loff[NB_MAX];         // 6400 B
    __shared__ int lcur[NB_MAX];         // 6400 B
    __shared__ int part[256];            // 1024 B  (total 65024 <= 64 KB)
    int tb = blockIdx.x, t = threadIdx.x;
    int base = tb * T_EDGES;
    int n = min(T_EDGES, E - base);

    // local exclusive scan of this tile's hist row -> loff, lcur
    int chunk = (NB + 255) / 256;
    int lo = t * chunk, hi = min(lo + chunk, NB);
    int s = 0;
    for (int i = lo; i < hi; i++) {
        int c = ghist[(size_t)tb * NB + i];
        loff[i] = c;  // temp: counts
        s += c;
    }
    part[t] = s;
    __syncthreads();
    for (int off = 1; off < 256; off <<= 1) {
        int x = (t >= off) ? part[t - off] : 0;
        __syncthreads();
        part[t] += x;
        __syncthreads();
    }
    int run = part[t] - s;
    for (int i = lo; i < hi; i++) {
        int c = loff[i];
        loff[i] = run;
        lcur[i] = run;
        run += c;
    }
    __syncthreads();

    // rank phase: perm[pos within tile] = local_idx | bucket<<14 | localdst<<25
    for (int i = t; i < n; i += 256) {
        int d = dst[base + i];
        unsigned b = ((unsigned)d) >> 6;
        int p = atomicAdd(&lcur[b], 1);       // LDS atomic, avg 8/bin
        perm[p] = (unsigned)i | (b << 14) | ((unsigned)(d & 63) << 25);
    }
    __syncthreads();

    // output phase: coalesced-run stores to exact global positions
    for (int o = t; o < n; o += 256) {
        unsigned v = perm[o];
        int li = v & 16383;
        int b  = (v >> 14) & 2047;
        int ld = v >> 25;
        int g  = goff[(size_t)tb * NB + b] + (o - loff[b]);
        edges[g] = make_int2(src[base + li] | (ld << 17), __float_as_int(val[base + li]));
    }
}

// ---- finalize: per-bucket LDS reorder, sort by local dst (enables run-accum) ----
__global__ __launch_bounds__(256) void finalize_kernel(int2* __restrict__ edges,
                                                       const int* __restrict__ bucket_ptr) {
    __shared__ int2 recs[FCAP];
    __shared__ int2 recs2[FCAP];
    __shared__ int cnt[64], offs[64], cur[64];
    int b = blockIdx.x, t = threadIdx.x;
    int s0 = bucket_ptr[b], s1 = bucket_ptr[b + 1];
    int ne = min(s1 - s0, FCAP);
    if (t < 64) cnt[t] = 0;
    __syncthreads();
    for (int i = t; i < ne; i += 256) {
        int2 r = edges[s0 + i];
        recs[i] = r;
        atomicAdd(&cnt[(r.x >> 17) & 63], 1);
    }
    __syncthreads();
    if (t == 0) {
        int run = 0;
        for (int i = 0; i < 64; i++) { offs[i] = run; run += cnt[i]; }
    }
    __syncthreads();
    if (t < 64) cur[t] = offs[t];
    __syncthreads();
    for (int i = t; i < ne; i += 256) {
        int2 r = recs[i];
        int ld = (r.x >> 17) & 63;
        int p = atomicAdd(&cur[ld], 1);
        recs2[p] = r;                         // keep ld packed for gather
    }
    __syncthreads();
    for (int i = t; i < ne; i += 256) edges[s0 + i] = recs2[i];  // coalesced
}

// ---- layer 1 dense: s1 = x @ W1  (N x 512) @ (512 x 12), out stride 12 ----
__global__ __launch_bounds__(256) void dense1_kernel(const float* __restrict__ x,
                                                     const float* __restrict__ W,
                                                     float* __restrict__ out, int N) {
    __shared__ float xs[256 * 33];
    const int t    = threadIdx.x;
    const int row0 = blockIdx.x * 256;
    const int r    = row0 + t;

    float acc[12];
#pragma unroll
    for (int j = 0; j < 12; j++) acc[j] = 0.f;

    for (int tile = 0; tile < 16; ++tile) {
#pragma unroll
        for (int i = 0; i < 8; i++) {
            int idx4 = t + 256 * i;
            int flat = idx4 * 4;
            int rl   = flat >> 5;
            int c    = flat & 31;
            int rg   = row0 + rl;
            if (rg >= N) rg = N - 1;
            const float4 v = *(const float4*)(x + (size_t)rg * 512 + tile * 32 + c);
            float* p = &xs[rl * 33 + c];
            p[0] = v.x; p[1] = v.y; p[2] = v.z; p[3] = v.w;
        }
        __syncthreads();
#pragma unroll 8
        for (int kk = 0; kk < 32; ++kk) {
            float xv = xs[t * 33 + kk];
            int k = tile * 32 + kk;
#pragma unroll
            for (int j = 0; j < 12; j++) acc[j] += xv * W[k * 12 + j];
        }
        __syncthreads();
    }
    if (r < N) {
#pragma unroll
        for (int j = 0; j < 12; j++) out[(size_t)r * 12 + j] = acc[j];
    }
}

// ---- bucket-parallel fused layer:
//   agg_k (CSR gather, run-accumulated) + h=act(agg+b_k) + s_{k+1}=h@W_{k+1}
// NV = float4s per input s-row (input stride = 4*NV floats, pads zeroed).
// ACT: 0 none, 1 relu, 2 tanhshrink.  FINAL: write h (=agg+b) as DIN floats.
template <int NV, int DIN, int DOUT, int OSTR, int ACT, bool FINAL>
__global__ __launch_bounds__(256) void layer_kernel(const int2* __restrict__ edges,
                                                    const int* __restrict__ bucket_ptr,
                                                    const float* __restrict__ s,
                                                    const float* __restrict__ bias,
                                                    const float* __restrict__ W,
                                                    float* __restrict__ out, int N) {
    constexpr int ASTR = 13;                 // padded acc stride (conflict-free)
    __shared__ int2  ebuf[FCAP];             // 20480 B
    __shared__ float acc[64 * ASTR];         // 3328 B
    const int b = blockIdx.x, t = threadIdx.x;
    const int s0 = bucket_ptr[b];
    const int ne = min(bucket_ptr[b + 1] - s0, FCAP);

    for (int i = t; i < 64 * ASTR; i += 256) acc[i] = 0.f;
    for (int i = t; i < ne; i += 256) ebuf[i] = edges[s0 + i];  // coalesced stage
    __syncthreads();

    // per-thread contiguous chunk of sorted edges; run-accumulate in registers
    const int K  = (ne + 255) >> 8;          // <= 10
    const int i0 = t * K;
    const int i1 = min(i0 + K, ne);
    if (i0 < i1) {
        const float4* sv = (const float4*)s;
        float4 a[NV];
#pragma unroll
        for (int v = 0; v < NV; v++) a[v] = make_float4(0.f, 0.f, 0.f, 0.f);
        int cd = (ebuf[i0].x >> 17) & 63;
        for (int i = i0; i < i1; ++i) {
            int2 ev = ebuf[i];
            int ld = (ev.x >> 17) & 63;
            if (ld != cd) {
#pragma unroll
                for (int v = 0; v < NV; v++) {
                    atomicAdd(&acc[cd * ASTR + 4 * v + 0], a[v].x);
                    atomicAdd(&acc[cd * ASTR + 4 * v + 1], a[v].y);
                    atomicAdd(&acc[cd * ASTR + 4 * v + 2], a[v].z);
                    atomicAdd(&acc[cd * ASTR + 4 * v + 3], a[v].w);
                    a[v] = make_float4(0.f, 0.f, 0.f, 0.f);
                }
                cd = ld;
            }
            float w = __int_as_float(ev.y);
            const float4* srow = sv + (size_t)(ev.x & 0x1FFFF) * NV;
#pragma unroll
            for (int v = 0; v < NV; v++) {
                float4 xr = srow[v];
                a[v].x += w * xr.x; a[v].y += w * xr.y;
                a[v].z += w * xr.z; a[v].w += w * xr.w;
            }
        }
#pragma unroll
        for (int v = 0; v < NV; v++) {
            atomicAdd(&acc[cd * ASTR + 4 * v + 0], a[v].x);
            atomicAdd(&acc[cd * ASTR + 4 * v + 1], a[v].y);
            atomicAdd(&acc[cd * ASTR + 4 * v + 2], a[v].z);
            atomicAdd(&acc[cd * ASTR + 4 * v + 3], a[v].w);
        }
    }
    __syncthreads();

    // epilogue: node-per-thread (t<64), bias+act, next dense, coalesced store
    if (t < 64) {
        int node = (b << 6) + t;
        if (node < N) {
            float h[DIN];
#pragma unroll
            for (int k = 0; k < DIN; k++) {
                float z = acc[t * ASTR + k] + bias[k];   // bias: s_load
                if (ACT == 1) z = fmaxf(z, 0.f);
                else if (ACT == 2) z = z - tanhf(z);
                h[k] = z;
            }
            if (FINAL) {
#pragma unroll
                for (int k = 0; k < DIN; k++) out[(size_t)node * DIN + k] = h[k];
            } else {
                float o[OSTR];
#pragma unroll
                for (int j = 0; j < OSTR; j++) o[j] = 0.f;  // zero pads
#pragma unroll
                for (int j = 0; j < DOUT; j++) {
                    float tj = 0.f;
#pragma unroll
                    for (int k = 0; k < DIN; k++) tj += h[k] * W[k * DOUT + j];  // s_load
                    o[j] = tj;
                }
                float4* orow = (float4*)(out + (size_t)node * OSTR);
#pragma unroll
                for (int v = 0; v < OSTR / 4; v++)
                    orow[v] = make_float4(o[4 * v], o[4 * v + 1], o[4 * v + 2], o[4 * v + 3]);
            }
        }
    }
}

// ---------------- launcher ----------------

static inline size_t align256(size_t x) { return (x + 255) & ~(size_t)255; }

extern "C" void kernel_launch(void* const* d_in, const int* in_sizes, int n_in,
                              void* d_out, int out_size, void* d_ws, size_t ws_size,
                              hipStream_t stream) {
    const float* x        = (const float*)d_in[0];
    const float* edge_val = (const float*)d_in[1];
    const int*   edge_src = (const int*)d_in[2];
    const int*   edge_dst = (const int*)d_in[3];
    const float* W1 = (const float*)d_in[4];   const float* b1 = (const float*)d_in[5];
    const float* W2 = (const float*)d_in[6];   const float* b2 = (const float*)d_in[7];
    const float* W3 = (const float*)d_in[8];   const float* b3 = (const float*)d_in[9];
    const float* W4 = (const float*)d_in[10];  const float* b4 = (const float*)d_in[11];
    const float* W5 = (const float*)d_in[12];  const float* b5 = (const float*)d_in[13];
    const float* W6 = (const float*)d_in[14];  const float* b6 = (const float*)d_in[15];

    const int N = in_sizes[0] / 512;        // 100000
    const int E = in_sizes[1];              // 3200000
    float* out = (float*)d_out;

    const int NB = (N + 63) >> 6;           // 1563 fine buckets
    const int NT = (E + T_EDGES - 1) / T_EDGES;  // 250 tiles (<=256 required)
    const int nb = (N + 255) / 256;

    // workspace carve-up (~38.7 MB)
    char* w = (char*)d_ws;
    float* A          = (float*)w;  w += align256((size_t)N * 12 * sizeof(float));
    float* B          = (float*)w;  w += align256((size_t)N * 12 * sizeof(float));
    int*   ghist      = (int*)w;    w += align256((size_t)NT * NB * sizeof(int));
    int*   goff       = (int*)w;    w += align256((size_t)NT * NB * sizeof(int));
    int*   btot       = (int*)w;    w += align256((size_t)NB * sizeof(int));
    int*   bbase      = (int*)w;    w += align256((size_t)NB * sizeof(int));
    int*   bucket_ptr = (int*)w;    w += align256((size_t)(NB + 1) * sizeof(int));
    int2*  edges      = (int2*)w;   w += align256((size_t)E * sizeof(int2));

    // ---- CSR build: atomic-free radix partition ----
    hist_kernel<<<NT, 256, 0, stream>>>(edge_dst, ghist, E, NB);
    scanA_kernel<<<NB, 256, 0, stream>>>(ghist, btot, NT, NB);
    scanB_kernel<<<1, 256, 0, stream>>>(btot, bbase, bucket_ptr, NB);
    scanC_kernel<<<NB, 256, 0, stream>>>(ghist, bbase, goff, NT, NB);
    scatter_kernel<<<NT, 256, 0, stream>>>(edge_src, edge_dst, edge_val, ghist, goff, edges, E, NB);
    finalize_kernel<<<NB, 256, 0, stream>>>(edges, bucket_ptr);

    // ---- dense1: s1 = x @ W1 (stride 12) ----
    dense1_kernel<<<nb, 256, 0, stream>>>(x, W1, A, N);

    // ---- fused bucket-parallel gather+dense chain ----
    // G1: agg1 -> h1=agg+b1 -> s2=h1@W2 (12->10, out stride 12)
    layer_kernel<3, 12, 10, 12, 0, false><<<NB, 256, 0, stream>>>(edges, bucket_ptr, A, b1, W2, B, N);
    // G2: agg2 -> h2=relu -> s3=h2@W3 (10->8, out stride 8)
    layer_kernel<3, 10, 8, 8, 1, false><<<NB, 256, 0, stream>>>(edges, bucket_ptr, B, b2, W3, A, N);
    // G3: agg3 -> h3=ts -> s4=h3@W4 (8->6, out stride 8)
    layer_kernel<2, 8, 6, 8, 2, false><<<NB, 256, 0, stream>>>(edges, bucket_ptr, A, b3, W4, B, N);
    // G4: agg4 -> h4=ts -> s5=h4@W5 (6->4, out stride 4)
    layer_kernel<2, 6, 4, 4, 2, false><<<NB, 256, 0, stream>>>(edges, bucket_ptr, B, b4, W5, A, N);
    // G5: agg5 -> h5=agg+b5 -> s6=h5@W6 (4->7, out stride 8)
    layer_kernel<1, 4, 7, 8, 0, false><<<NB, 256, 0, stream>>>(edges, bucket_ptr, A, b5, W6, B, N);
    // G6: out = agg6 + b6 (7 floats, exact layout)
    layer_kernel<2, 7, 7, 8, 0, true><<<NB, 256, 0, stream>>>(edges, bucket_ptr, B, b6, (const float*)nullptr, out, N);
}